// Round 4
// baseline (147.929 us; speedup 1.0000x reference)
//
#include <hip/hip_runtime.h>
#include <math.h>

#define BB 2
#define TT 512
#define UU 48
#define DD 512
#define HH 1024
#define KK 128

typedef __bf16 bf16x8 __attribute__((ext_vector_type(8)));
typedef float floatx4 __attribute__((ext_vector_type(4)));

// Padé(5,4) tanh: |err| < ~1e-3 for all x (clamped), no transcendentals.
__device__ __forceinline__ float tanh_fast(float x) {
    float x2 = x * x;
    float num = x * fmaf(x2, x2 + 105.0f, 945.0f);
    float den = fmaf(x2, fmaf(x2, 15.0f, 420.0f), 945.0f);
    float r = num * __fdividef(1.0f, den);
    return fminf(1.0f, fmaxf(-1.0f, r));
}

// ---------------- mid: imgH/labH/seg GEMMs + W2 swizzle, one dispatch -------
// region 0 (bid<256):   imgHb[r][n] = bf16(img·Wi)            M=1024 N=1024 K=512
// region 1 (256..279):  labHb[r][n] = bf16(lab·Wl + b1)       M=96   N=1024 K=512
// region 2 (280..311):  seg[b][k][t] = (img·cw + cb)*mask     M=1024 N=128  K=512
// region 3 (312..327):  W2s swizzle fp32->bf16
__global__ __launch_bounds__(256) void mid_kernel2(
    const float* __restrict__ img, const float* __restrict__ labf,
    const float* __restrict__ W1, const float* __restrict__ W2,
    const float* __restrict__ conv_w,
    const float* __restrict__ b1, const float* __restrict__ conv_b,
    const float* __restrict__ masks,
    __bf16* __restrict__ imgHb, __bf16* __restrict__ labHb,
    __bf16* __restrict__ W2s, float* __restrict__ seg_out) {
    int bid = blockIdx.x, tid = threadIdx.x;
    if (bid >= 312) {  // W2 swizzle: W2s[(h>>3)*1024 + k*8 + (h&7)] = W2[k][h]
        int base = (bid - 312) * 256 + tid;
#pragma unroll
        for (int i = 0; i < 32; ++i) {
            int o = base + i * 4096;
            int hg = o >> 10, kk2 = (o >> 3) & 127, hl = o & 7;
            W2s[o] = (__bf16)W2[(size_t)kk2 * HH + hg * 8 + hl];
        }
        return;
    }
    __shared__ __align__(16) __bf16 a_s[32][72];
    __shared__ __align__(16) __bf16 w_s[8192];
    const float* Arow;
    const float* Wbase;
    int r0, n0b, wstride, region;
    if (bid < 256) {
        region = 0; Arow = img; Wbase = W1 + 512; wstride = 1024;
        r0 = (bid & 31) * 32; n0b = (bid >> 5) * 128;
    } else if (bid < 280) {
        region = 1; Arow = labf; Wbase = W1; wstride = 1024;
        int i = bid - 256; r0 = (i % 3) * 32; n0b = (i / 3) * 128;
    } else {
        region = 2; Arow = img; Wbase = conv_w; wstride = 512;
        r0 = (bid - 280) * 32; n0b = 0;
    }
    int lane = tid & 63, wv = tid >> 6;
    int m0 = (wv & 1) * 16, n0w = (wv >> 1) * 64;
    int q = lane >> 4, r = lane & 15;
    int arow = tid >> 3, acol = (tid & 7) * 8;
    floatx4 acc[4] = {};
    for (int c = 0; c < 8; ++c) {
        int cb = c * 64;
        {   // A tile fp32 -> bf16
            const float* ap = &Arow[(size_t)(r0 + arow) * DD + cb + acol];
            float4 a0 = *(const float4*)ap;
            float4 a1 = *(const float4*)(ap + 4);
            bf16x8 av;
            av[0] = (__bf16)a0.x; av[1] = (__bf16)a0.y;
            av[2] = (__bf16)a0.z; av[3] = (__bf16)a0.w;
            av[4] = (__bf16)a1.x; av[5] = (__bf16)a1.y;
            av[6] = (__bf16)a1.z; av[7] = (__bf16)a1.w;
            *(bf16x8*)&a_s[arow][acol] = av;
        }
#pragma unroll
        for (int i2 = 0; i2 < 4; ++i2) {  // W chunk: strided fp32 -> swizzled bf16
            int g = i2 * 256 + tid;
            int kg = g >> 7, n = g & 127;
            const float* wp = &Wbase[(size_t)(n0b + n) * wstride + cb + kg * 8];
            float4 w0 = *(const float4*)wp;
            float4 w1 = *(const float4*)(wp + 4);
            bf16x8 wvv;
            wvv[0] = (__bf16)w0.x; wvv[1] = (__bf16)w0.y;
            wvv[2] = (__bf16)w0.z; wvv[3] = (__bf16)w0.w;
            wvv[4] = (__bf16)w1.x; wvv[5] = (__bf16)w1.y;
            wvv[6] = (__bf16)w1.z; wvv[7] = (__bf16)w1.w;
            *(bf16x8*)&w_s[g * 8] = wvv;
        }
        __syncthreads();
#pragma unroll
        for (int kt = 0; kt < 2; ++kt) {
            bf16x8 af = *(const bf16x8*)&a_s[m0 + r][kt * 32 + q * 8];
#pragma unroll
            for (int nt = 0; nt < 4; ++nt) {
                bf16x8 bfv = *(const bf16x8*)
                    &w_s[((kt * 4 + q) * 128 + n0w + nt * 16 + r) * 8];
                acc[nt] = __builtin_amdgcn_mfma_f32_16x16x32_bf16(
                    af, bfv, acc[nt], 0, 0, 0);
            }
        }
        __syncthreads();
    }
    if (region == 0) {
#pragma unroll
        for (int nt = 0; nt < 4; ++nt) {
            int n = n0b + n0w + nt * 16 + r;
#pragma unroll
            for (int rr = 0; rr < 4; ++rr)
                imgHb[(size_t)(r0 + m0 + 4 * q + rr) * HH + n] =
                    (__bf16)acc[nt][rr];
        }
    } else if (region == 1) {
#pragma unroll
        for (int nt = 0; nt < 4; ++nt) {
            int n = n0b + n0w + nt * 16 + r;
            float bv = b1[n];
#pragma unroll
            for (int rr = 0; rr < 4; ++rr)
                labHb[(size_t)(r0 + m0 + 4 * q + rr) * HH + n] =
                    (__bf16)(acc[nt][rr] + bv);
        }
    } else {
#pragma unroll
        for (int nt = 0; nt < 4; ++nt) {
            int k = n0w + nt * 16 + r;
            float bv = conv_b[k];
#pragma unroll
            for (int rr = 0; rr < 4; ++rr) {
                int row = r0 + m0 + 4 * q + rr;
                int b = row >> 9, t = row & 511;
                seg_out[((size_t)b * KK + k) * TT + t] =
                    (acc[nt][rr] + bv) * masks[row];
            }
        }
    }
}

// ---------------- joint: dbuf pipeline, 1 barrier/chunk, bf16 in, reg softmax
__global__ __launch_bounds__(256, 3) void joint_kernel3(
    const __bf16* __restrict__ imgHb,  // [B*T][H]
    const __bf16* __restrict__ labHb,  // [B*U][H] (b1 folded)
    const __bf16* __restrict__ W2s,    // swizzled
    const float* __restrict__ b2,
    float* __restrict__ out) {         // [B*U*T][K]
    __shared__ __align__(16) __bf16 h_s[2][64][72];
    __shared__ __align__(16) __bf16 w_s[2][8192];
    int tid = threadIdx.x, bid = blockIdx.x;
    int t0 = (bid & 7) * 64;
    int rest = bid >> 3;
    int u = rest % UU, b = rest / UU;
    const __bf16* imgrow = imgHb + ((size_t)b * TT + t0) * HH;
    const __bf16* labrow = labHb + ((size_t)b * UU + u) * HH;
    int lane = tid & 63, wv = tid >> 6;
    int m0 = wv * 16;
    int q = lane >> 4, r = lane & 15;
    int srow2 = (tid >> 3) * 2, scol = (tid & 7) * 8;
    floatx4 acc[8] = {};
    bf16x8 iv0, iv1, lv, wr0, wr1, wr2, wr3;
    {   // prologue: chunk 0 into regs
        iv0 = *(const bf16x8*)&imgrow[(size_t)srow2 * HH + scol];
        iv1 = *(const bf16x8*)&imgrow[(size_t)(srow2 + 1) * HH + scol];
        lv  = *(const bf16x8*)&labrow[scol];
        wr0 = *(const bf16x8*)&W2s[(0 * 256 + tid) * 8];
        wr1 = *(const bf16x8*)&W2s[(1 * 256 + tid) * 8];
        wr2 = *(const bf16x8*)&W2s[(2 * 256 + tid) * 8];
        wr3 = *(const bf16x8*)&W2s[(3 * 256 + tid) * 8];
    }
#pragma unroll 2
    for (int c = 0; c < 16; ++c) {
        int buf = c & 1;
        *(bf16x8*)&w_s[buf][(0 * 256 + tid) * 8] = wr0;
        *(bf16x8*)&w_s[buf][(1 * 256 + tid) * 8] = wr1;
        *(bf16x8*)&w_s[buf][(2 * 256 + tid) * 8] = wr2;
        *(bf16x8*)&w_s[buf][(3 * 256 + tid) * 8] = wr3;
        {   // tanh(img + lab) -> bf16 LDS
            bf16x8 h0, h1;
#pragma unroll
            for (int i = 0; i < 8; ++i) {
                float xl = (float)lv[i];
                h0[i] = (__bf16)tanh_fast((float)iv0[i] + xl);
                h1[i] = (__bf16)tanh_fast((float)iv1[i] + xl);
            }
            *(bf16x8*)&h_s[buf][srow2][scol] = h0;
            *(bf16x8*)&h_s[buf][srow2 + 1][scol] = h1;
        }
        __syncthreads();
        if (c < 15) {  // issue next chunk's loads; latency hides under MFMA
            int cb = (c + 1) * 64;
            iv0 = *(const bf16x8*)&imgrow[(size_t)srow2 * HH + cb + scol];
            iv1 = *(const bf16x8*)&imgrow[(size_t)(srow2 + 1) * HH + cb + scol];
            lv  = *(const bf16x8*)&labrow[cb + scol];
            const __bf16* wsrc = W2s + (size_t)cb * KK;
            wr0 = *(const bf16x8*)&wsrc[(0 * 256 + tid) * 8];
            wr1 = *(const bf16x8*)&wsrc[(1 * 256 + tid) * 8];
            wr2 = *(const bf16x8*)&wsrc[(2 * 256 + tid) * 8];
            wr3 = *(const bf16x8*)&wsrc[(3 * 256 + tid) * 8];
        }
#pragma unroll
        for (int kt = 0; kt < 2; ++kt) {
            bf16x8 af = *(const bf16x8*)&h_s[buf][m0 + r][kt * 32 + q * 8];
#pragma unroll
            for (int nt = 0; nt < 8; ++nt) {
                bf16x8 bfv = *(const bf16x8*)
                    &w_s[buf][((kt * 4 + q) * 128 + nt * 16 + r) * 8];
                acc[nt] = __builtin_amdgcn_mfma_f32_16x16x32_bf16(
                    af, bfv, acc[nt], 0, 0, 0);
            }
        }
    }
    // epilogue: +b2, in-register log-softmax over the 128 cols of this 16-lane group
    float b2v[8];
#pragma unroll
    for (int nt = 0; nt < 8; ++nt) b2v[nt] = b2[nt * 16 + r];
    float* orow = out + (((size_t)b * UU + u) * TT + t0 + m0) * KK;
#pragma unroll
    for (int rr = 0; rr < 4; ++rr) {
        float v[8];
        float mx = -INFINITY;
#pragma unroll
        for (int nt = 0; nt < 8; ++nt) {
            v[nt] = acc[nt][rr] + b2v[nt];
            mx = fmaxf(mx, v[nt]);
        }
        mx = fmaxf(mx, __shfl_xor(mx, 1, 16));
        mx = fmaxf(mx, __shfl_xor(mx, 2, 16));
        mx = fmaxf(mx, __shfl_xor(mx, 4, 16));
        mx = fmaxf(mx, __shfl_xor(mx, 8, 16));
        float s = 0.f;
#pragma unroll
        for (int nt = 0; nt < 8; ++nt) s += __expf(v[nt] - mx);
        s += __shfl_xor(s, 1, 16);
        s += __shfl_xor(s, 2, 16);
        s += __shfl_xor(s, 4, 16);
        s += __shfl_xor(s, 8, 16);
        float lse = mx + __logf(s);
        int row = 4 * q + rr;
#pragma unroll
        for (int nt = 0; nt < 8; ++nt)
            orow[(size_t)row * KK + nt * 16 + r] = v[nt] - lse;
    }
}

extern "C" void kernel_launch(void* const* d_in, const int* in_sizes, int n_in,
                              void* d_out, int out_size, void* d_ws, size_t ws_size,
                              hipStream_t stream) {
    const float* img    = (const float*)d_in[0];
    const float* labf   = (const float*)d_in[1];
    const float* masks  = (const float*)d_in[2];
    const float* W1     = (const float*)d_in[3];
    const float* b1     = (const float*)d_in[4];
    const float* W2     = (const float*)d_in[5];
    const float* b2     = (const float*)d_in[6];
    const float* conv_w = (const float*)d_in[7];
    const float* conv_b = (const float*)d_in[8];
    float* out = (float*)d_out;

    __bf16* base   = (__bf16*)d_ws;
    __bf16* imgHb  = base;                    // [1024][1024]
    __bf16* labHb  = imgHb + 1024 * 1024;     // [96][1024]
    __bf16* W2s    = labHb + 96 * 1024;       // [H/8][K][8] = 131072

    mid_kernel2<<<328, 256, 0, stream>>>(img, labf, W1, W2, conv_w,
                                         b1, conv_b, masks,
                                         imgHb, labHb, W2s, out);
    joint_kernel3<<<768, 256, 0, stream>>>(imgHb, labHb, W2s, b2,
                                           out + (size_t)BB * KK * TT);
}